// Round 22
// baseline (41.639 us; speedup 1.0000x reference)
//
#include <hip/hip_runtime.h>

// TrueRingDilatedAttention R22 — 4-way split-K at 3 waves/SIMD.
// Identity 1: gathered K/V (4096) = each of 1024 local keys exactly 4x
//   -> softmax over 1024 distinct keys; denom = 4*S + EPS; out = 4*PV/denom.
// Identity 2: out = PV'/l' with p' = exp(s - 2) (shift-invariant; EPS dropped).
// Identity 3: PV swapped, O^T = mfma(A=V^T, B=P^T), k-slots pi-permuted on
//   both operands so lane (g,c)'s B-frag is its OWN cvt_pkrtz output words.
// Identity 4: K scaled log2e/8 + QK C-init = -2*log2e -> p = exp2(s_out).
// R21 post-mortem: memory exonerated; stall = dependency latency at 2
//   waves/SIMD. R19 body = 112 VGPR + 64 AGPR = 176 unified, 6 regs from
//   the 3-waves threshold (170). R22: per-t exp trims s-liveness 16->4;
//   launch_bounds(256,3) caps at 170; 4 waves/block (keys quartered, 4
//   tiles/wave) -> 4096 waves = 3 resident/SIMD (+50% TLP). Traffic
//   unchanged. Combine = R13 2-round LDS tree. WRITE_SIZE = spill sentinel.

typedef __attribute__((ext_vector_type(8))) _Float16 f16x8;   // 4 VGPRs
typedef __attribute__((ext_vector_type(2))) __fp16   h16x2;   // builtin type
typedef __attribute__((ext_vector_type(4))) float    f32x4;
typedef __attribute__((ext_vector_type(4))) int      i32x4;

constexpr int HEADS = 16;
constexpr int NQ    = 4096;
constexpr int NK    = 1024;
constexpr int KB    = 64;        // keys per tile
constexpr int NT    = NK / KB;   // 16 tiles total
constexpr int NTW   = NT / 4;    // 4 tiles per wave (4-way split-K)

constexpr int IMG_K  = 0;        // 8KB K fragment stream (QK^T A operand)
constexpr int IMG_V  = 8192;     // 8KB V^T A-frag stream (PV, pi-permuted k)
constexpr int IMG_SZ = 16384;

constexpr float KSCALE = 0.18033688011112042f;   // log2(e)/8
constexpr float CINIT  = -2.8853900817779268f;   // -2*log2(e)

// ---------------- pre-pass: build per-(h,kt) fragment streams ----------------
__global__ __launch_bounds__(256)
void prepass(const float* __restrict__ kg, const float* __restrict__ vg,
             char* __restrict__ ws)
{
    const int kt = blockIdx.x;
    const int h  = blockIdx.y;
    const int kb = kt * KB;
    char* img = ws + (size_t)(h * NT + kt) * IMG_SZ;
    const int tid = threadIdx.x;

    // K frags: unit u = f*64 + lane, f = t*2+cc.
    // lane (g,c) of frag (t,cc): K[kb+16t+c][32cc+8g+e], scaled log2e/8.
    #pragma unroll
    for (int i = 0; i < 2; ++i) {
        int u = i * 256 + tid;
        int f = u >> 6, l = u & 63;
        int t = f >> 1, cc = f & 1;
        int g = l >> 4, c = l & 15;
        const float* src = kg + (size_t)(kb + 16 * t + c) * 1024 + h * 64 + 32 * cc + 8 * g;
        float4 a = *(const float4*)src;
        float4 b = *(const float4*)(src + 4);
        f16x8 kk;
        kk[0] = (_Float16)(a.x * KSCALE); kk[1] = (_Float16)(a.y * KSCALE);
        kk[2] = (_Float16)(a.z * KSCALE); kk[3] = (_Float16)(a.w * KSCALE);
        kk[4] = (_Float16)(b.x * KSCALE); kk[5] = (_Float16)(b.y * KSCALE);
        kk[6] = (_Float16)(b.z * KSCALE); kk[7] = (_Float16)(b.w * KSCALE);
        *(f16x8*)(img + IMG_K + u * 16) = kk;
    }

    // V^T A-frags with k-permutation: unit u = f*64 + lane, f = m*4 + td.
    // lane (g,c), elem e: V[kb + 32m + 16*(e>>2) + 4g + (e&3)][h*64+16td+c]
    #pragma unroll
    for (int i = 0; i < 2; ++i) {
        int u = i * 256 + tid;
        int f = u >> 6, l = u & 63;
        int m = f >> 2, td = f & 3;
        int g = l >> 4, c = l & 15;
        f16x8 vv;
        #pragma unroll
        for (int e = 0; e < 8; ++e) {
            int key = kb + 32 * m + 16 * (e >> 2) + 4 * g + (e & 3);
            vv[e] = (_Float16)vg[(size_t)key * 1024 + h * 64 + 16 * td + c];
        }
        *(f16x8*)(img + IMG_V + u * 16) = vv;
    }
}

// ---- main: 64 q/block, 4-wave split-K (256 keys/wave), register-only P ----
__global__ __launch_bounds__(256, 3)
void ring_attn_v22(const float* __restrict__ qg,
                   const char* __restrict__ ws,
                   float* __restrict__ outg)
{
    __shared__ __align__(16) float Ob2[2][64 * 68 + 64];   // combine tree bufs

    // XCD-aware swizzle: xcd = bid&7; each XCD runs heads {2*xcd, 2*xcd+1}.
    const int bid  = blockIdx.x;            // 0..1023
    const int xcd  = bid & 7;
    const int slot = bid >> 3;              // 0..127
    const int h    = xcd * 2 + (slot >> 6);
    const int qw   = slot & 63;             // q-block (64 q) within head

    const int tid  = threadIdx.x;
    const int w    = tid >> 6;         // key quarter: [w*256, w*256+256)
    const int lane = tid & 63;
    const int g    = lane >> 4;
    const int c    = lane & 15;
    const int qbase = qw * 64;

    // de-phase co-resident waves' tile rings (within the 4-tile quarter)
    const int rot  = ((bid >> 3) ^ w) & 3;

    // ---- Q fragments fp16 (log2e/8 scale folded into K): 4 halves x 2 cc
    f16x8 qf[4][2];
    #pragma unroll
    for (int H = 0; H < 4; ++H)
        #pragma unroll
        for (int cc = 0; cc < 2; ++cc) {
            const float* src = qg + (size_t)(qbase + 16 * H + c) * 1024 + h * 64 + 32 * cc + 8 * g;
            float4 a = *(const float4*)src;
            float4 b = *(const float4*)(src + 4);
            f16x8 qq;
            qq[0] = (_Float16)a.x; qq[1] = (_Float16)a.y;
            qq[2] = (_Float16)a.z; qq[3] = (_Float16)a.w;
            qq[4] = (_Float16)b.x; qq[5] = (_Float16)b.y;
            qq[6] = (_Float16)b.z; qq[7] = (_Float16)b.w;
            qf[H][cc] = qq;
        }

    const f32x4 zero4 = {0.f, 0.f, 0.f, 0.f};
    const f32x4 cinit = {CINIT, CINIT, CINIT, CINIT};
    const h16x2 ones2 = {(__fp16)1.f, (__fp16)1.f};

    f32x4 o[4][4];                     // [half][td] : O^T[d=16td+4g+r][q=c]
    #pragma unroll
    for (int H = 0; H < 4; ++H)
        #pragma unroll
        for (int td = 0; td < 4; ++td) o[H][td] = zero4;
    float lac[4] = {0.f, 0.f, 0.f, 0.f};

    const char* himg = ws + (size_t)h * NT * IMG_SZ + lane * 16;

    #pragma unroll 1
    for (int i = 0; i < NTW; ++i) {
        const int kt = w * NTW + ((i + rot) & 3);
        const char* img = himg + (size_t)kt * IMG_SZ;

        // ---- K frags -> time-shared kv buffer (32 VGPR)
        f16x8 kv[8];
        #pragma unroll
        for (int f = 0; f < 8; ++f)
            kv[f] = *(const f16x8*)(img + IMG_K + f * 1024);

        // ---- per-(H,t) QK -> exp (s liveness = 4 regs; frees regs for occ.)
        unsigned int wv[4][4][2];      // [half][t][rp] packed f16x2 of P
        #pragma unroll
        for (int H = 0; H < 4; ++H) {
            #pragma unroll
            for (int t = 0; t < 4; ++t) {
                f32x4 s;
                s = __builtin_amdgcn_mfma_f32_16x16x32_f16(kv[2 * t],     qf[H][0], cinit, 0, 0, 0);
                s = __builtin_amdgcn_mfma_f32_16x16x32_f16(kv[2 * t + 1], qf[H][1], s,     0, 0, 0);
                float p0 = __builtin_amdgcn_exp2f(s[0]);
                float p1 = __builtin_amdgcn_exp2f(s[1]);
                float p2 = __builtin_amdgcn_exp2f(s[2]);
                float p3 = __builtin_amdgcn_exp2f(s[3]);
                h16x2 w0 = __builtin_amdgcn_cvt_pkrtz(p0, p1);
                h16x2 w1 = __builtin_amdgcn_cvt_pkrtz(p2, p3);
                lac[H] = __builtin_amdgcn_fdot2(w0, ones2, lac[H], false);
                lac[H] = __builtin_amdgcn_fdot2(w1, ones2, lac[H], false);
                wv[H][t][0] = __builtin_bit_cast(unsigned int, w0);
                wv[H][t][1] = __builtin_bit_cast(unsigned int, w1);
            }
        }

        // ---- V^T A-frags -> same kv regs (K dead after QK)
        #pragma unroll
        for (int f = 0; f < 8; ++f)
            kv[f] = *(const f16x8*)(img + IMG_V + f * 1024);

        // ---- PV swapped: O^T += mfma(A=V^T frag, B=own packed P words)
        __builtin_amdgcn_s_setprio(1);
        #pragma unroll
        for (int H = 0; H < 4; ++H) {
            i32x4 c0, c1;
            c0[0] = wv[H][0][0]; c0[1] = wv[H][0][1];
            c0[2] = wv[H][1][0]; c0[3] = wv[H][1][1];
            c1[0] = wv[H][2][0]; c1[1] = wv[H][2][1];
            c1[2] = wv[H][3][0]; c1[3] = wv[H][3][1];
            f16x8 B0 = __builtin_bit_cast(f16x8, c0);   // keys 0..31 (pi-order)
            f16x8 B1 = __builtin_bit_cast(f16x8, c1);   // keys 32..63
            #pragma unroll
            for (int td = 0; td < 4; ++td) {
                o[H][td] = __builtin_amdgcn_mfma_f32_16x16x32_f16(kv[td],     B0, o[H][td], 0, 0, 0);
                o[H][td] = __builtin_amdgcn_mfma_f32_16x16x32_f16(kv[4 + td], B1, o[H][td], 0, 0, 0);
            }
        }
        __builtin_amdgcn_s_setprio(0);
        // spill guard: keep next tile's loads out of this tile's body
        __builtin_amdgcn_sched_barrier(0);
    }

    // ---- reduce l across g-groups: every lane gets full l for q = own c
    #pragma unroll
    for (int H = 0; H < 4; ++H) {
        lac[H] += __shfl_xor(lac[H], 16);
        lac[H] += __shfl_xor(lac[H], 32);
    }

    // ---- 4-way split-K combine: 2-round LDS tree
    float* ObA = Ob2[0];
    float* ObB = Ob2[1];
    float* LsA = ObA + 64 * 68;
    float* LsB = ObB + 64 * 68;

    auto writePart = [&](float* Ob, float* Ls) {
        #pragma unroll
        for (int H = 0; H < 4; ++H)
            #pragma unroll
            for (int td = 0; td < 4; ++td) {
                float4 st;
                st.x = o[H][td][0]; st.y = o[H][td][1];
                st.z = o[H][td][2]; st.w = o[H][td][3];
                *(float4*)&Ob[(16 * H + c) * 68 + 16 * td + 4 * g] = st;
            }
        if (lane < 16) {
            #pragma unroll
            for (int H = 0; H < 4; ++H) Ls[16 * H + lane] = lac[H];
        }
    };
    auto addPart = [&](const float* Ob, const float* Ls) {
        #pragma unroll
        for (int H = 0; H < 4; ++H) {
            #pragma unroll
            for (int td = 0; td < 4; ++td) {
                float4 pb = *(const float4*)&Ob[(16 * H + c) * 68 + 16 * td + 4 * g];
                o[H][td][0] += pb.x; o[H][td][1] += pb.y;
                o[H][td][2] += pb.z; o[H][td][3] += pb.w;
            }
            lac[H] += Ls[16 * H + c];
        }
    };

    if (w == 2)      writePart(ObA, LsA);
    else if (w == 3) writePart(ObB, LsB);
    __syncthreads();
    if (w == 0)      addPart(ObA, LsA);
    else if (w == 1) addPart(ObB, LsB);
    __syncthreads();
    if (w == 1)      writePart(ObA, LsA);
    __syncthreads();

    if (w == 0) {
        addPart(ObA, LsA);
        #pragma unroll
        for (int H = 0; H < 4; ++H) {
            float inv = 1.f / lac[H];
            #pragma unroll
            for (int td = 0; td < 4; ++td) {
                float4 st;
                st.x = o[H][td][0] * inv; st.y = o[H][td][1] * inv;
                st.z = o[H][td][2] * inv; st.w = o[H][td][3] * inv;
                *(float4*)(outg + (size_t)(qbase + 16 * H + c) * 1024 + h * 64 + 16 * td + 4 * g) = st;
            }
        }
    }
}

extern "C" void kernel_launch(void* const* d_in, const int* in_sizes, int n_in,
                              void* d_out, int out_size, void* d_ws, size_t ws_size,
                              hipStream_t stream) {
    const float* q = (const float*)d_in[0];
    const float* k = (const float*)d_in[1];
    const float* v = (const float*)d_in[2];
    float* out = (float*)d_out;
    char* ws = (char*)d_ws;   // 16*16*16384 = 4 MB

    prepass<<<dim3(NT, HEADS), dim3(256), 0, stream>>>(k, v, ws);
    ring_attn_v22<<<dim3(1024), dim3(256), 0, stream>>>(q, ws, out);
}

// Round 23
// 35.354 us; speedup vs baseline: 1.1778x; 1.1778x over previous
//
#include <hip/hip_runtime.h>

// TrueRingDilatedAttention R23 — 32x32x16 MFMA (half the instructions).
// Identity 1: gathered K/V (4096) = each of 1024 local keys exactly 4x
//   -> softmax over 1024 distinct keys; denom = 4*S + EPS; out = 4*PV/denom.
// Identity 2: out = PV'/l' with p' = exp(s - 2) (shift-invariant).
// Identity 3: PV swapped, O^T = mfma(A=V^T, B=P^T), k-slots pi-permuted on
//   both operands: pi(8h+e) = (e&3) + 16*half + 8*(e>>2) + 4h  => lane's
//   PV B-frag is its OWN packed QK-exp output (regs 8*half..8*half+7).
// Identity 4: K scaled log2e/8 + QK C-init = -2*log2e -> p = exp2(s_out).
// Layouts (guide-verified C/D for 32x32: col=lane&31,
//   row=(reg&3)+8*(reg>>2)+4*(lane>>5); A/B: row/col=lane&31, k=8*(lane>>5)+e).
// R22 post-mortem: 3 waves/SIMD unreachable (spill at 170-reg cap).
//   Instruction cuts won 4/4 -> 32x32 halves MFMA count, +11% pipe rate.

typedef __attribute__((ext_vector_type(8)))  _Float16 f16x8;   // 4 VGPRs
typedef __attribute__((ext_vector_type(2)))  __fp16   h16x2;
typedef __attribute__((ext_vector_type(16))) float    f32x16;  // 16 VGPRs
typedef __attribute__((ext_vector_type(4)))  int      i32x4;

constexpr int HEADS = 16;
constexpr int NQ    = 4096;
constexpr int NK    = 1024;
constexpr int KB    = 64;        // keys per tile
constexpr int NT    = NK / KB;   // 16 tiles total
constexpr int NTW   = NT / 2;    // 8 tiles per wave (2-way split-K)

constexpr int IMG_K  = 0;        // 8KB K fragment stream (QK A operand)
constexpr int IMG_V  = 8192;     // 8KB V^T A-frag stream (PV, pi-permuted k)
constexpr int IMG_SZ = 16384;

constexpr float KSCALE = 0.18033688011112042f;   // log2(e)/8
constexpr float CINIT  = -2.8853900817779268f;   // -2*log2(e)

// ---------------- pre-pass: build per-(hd,kt) fragment streams ---------------
__global__ __launch_bounds__(256)
void prepass(const float* __restrict__ kg, const float* __restrict__ vg,
             char* __restrict__ ws)
{
    const int kt = blockIdx.x;
    const int hd = blockIdx.y;
    const int kb = kt * KB;
    char* img = ws + (size_t)(hd * NT + kt) * IMG_SZ;
    const int tid = threadIdx.x;

    // K frags (QK A, 32x32x16): frag f = kb2*4 + ks.
    // lane l elem e: K[kb + 32*kb2 + (l&31)][16*ks + 8*(l>>5) + e] * KSCALE
    #pragma unroll
    for (int i = 0; i < 2; ++i) {
        int u = i * 256 + tid;
        int f = u >> 6, l = u & 63;
        int kb2 = f >> 2, ks = f & 3;
        const float* src = kg + (size_t)(kb + 32 * kb2 + (l & 31)) * 1024
                              + hd * 64 + 16 * ks + 8 * (l >> 5);
        float4 a = *(const float4*)src;
        float4 b = *(const float4*)(src + 4);
        f16x8 kk;
        kk[0] = (_Float16)(a.x * KSCALE); kk[1] = (_Float16)(a.y * KSCALE);
        kk[2] = (_Float16)(a.z * KSCALE); kk[3] = (_Float16)(a.w * KSCALE);
        kk[4] = (_Float16)(b.x * KSCALE); kk[5] = (_Float16)(b.y * KSCALE);
        kk[6] = (_Float16)(b.z * KSCALE); kk[7] = (_Float16)(b.w * KSCALE);
        *(f16x8*)(img + IMG_K + u * 16) = kk;
    }

    // V^T frags (PV A, pi-permuted k): frag f = db*4 + kb2*2 + half.
    // lane l elem e: V[kb + 32*kb2 + (e&3)+16*half+8*(e>>2)+4*(l>>5)]
    //                 [hd*64 + 32*db + (l&31)]
    #pragma unroll
    for (int i = 0; i < 2; ++i) {
        int u = i * 256 + tid;
        int f = u >> 6, l = u & 63;
        int db = f >> 2, kb2 = (f >> 1) & 1, half = f & 1;
        int d31 = l & 31, hg = l >> 5;
        f16x8 vv;
        #pragma unroll
        for (int e = 0; e < 8; ++e) {
            int key = kb + 32 * kb2 + (e & 3) + 16 * half + 8 * (e >> 2) + 4 * hg;
            vv[e] = (_Float16)vg[(size_t)key * 1024 + hd * 64 + 32 * db + d31];
        }
        *(f16x8*)(img + IMG_V + u * 16) = vv;
    }
}

// --------- main: 64 q/wave, 2-wave split-K, register-only P, 32x32 ---------
__global__ __launch_bounds__(128, 2)
void ring_attn_v23(const float* __restrict__ qg,
                   const char* __restrict__ ws,
                   float* __restrict__ outg)
{
    __shared__ __align__(16) float Ob[64 * 68 + 64];   // combine + Ls tail

    // XCD-aware swizzle: each XCD runs heads {2*xcd, 2*xcd+1}.
    const int bid  = blockIdx.x;            // 0..1023
    const int xcd  = bid & 7;
    const int slot = bid >> 3;              // 0..127
    const int hd   = xcd * 2 + (slot >> 6);
    const int qw   = slot & 63;             // q-block (64 q) within head

    const int tid  = threadIdx.x;
    const int w    = tid >> 6;         // split index: keys [w*512, w*512+512)
    const int lane = tid & 63;
    const int q31  = lane & 31;
    const int hg   = lane >> 5;
    const int qbase = qw * 64;

    // de-phase co-resident waves' tile rings
    const int rot  = ((bid >> 3) ^ (w << 2)) & 7;

    // ---- Q frags (QK B): qf[qb][ks]; lane l elem e:
    //      Q[qbase+32*qb+(l&31)][16*ks + 8*(l>>5) + e]
    f16x8 qf[2][4];
    #pragma unroll
    for (int qb = 0; qb < 2; ++qb)
        #pragma unroll
        for (int ks = 0; ks < 4; ++ks) {
            const float* src = qg + (size_t)(qbase + 32 * qb + q31) * 1024
                                  + hd * 64 + 16 * ks + 8 * hg;
            float4 a = *(const float4*)src;
            float4 b = *(const float4*)(src + 4);
            f16x8 qq;
            qq[0] = (_Float16)a.x; qq[1] = (_Float16)a.y;
            qq[2] = (_Float16)a.z; qq[3] = (_Float16)a.w;
            qq[4] = (_Float16)b.x; qq[5] = (_Float16)b.y;
            qq[6] = (_Float16)b.z; qq[7] = (_Float16)b.w;
            qf[qb][ks] = qq;
        }

    f32x16 cinit16;
    #pragma unroll
    for (int j = 0; j < 16; ++j) cinit16[j] = CINIT;
    const h16x2 ones2 = {(__fp16)1.f, (__fp16)1.f};

    f32x16 o[2][2];                    // [qb][db] : O^T block accumulators
    #pragma unroll
    for (int qb = 0; qb < 2; ++qb)
        #pragma unroll
        for (int db = 0; db < 2; ++db)
            #pragma unroll
            for (int j = 0; j < 16; ++j) o[qb][db][j] = 0.f;
    float lac[2] = {0.f, 0.f};

    const char* himg = ws + (size_t)hd * NT * IMG_SZ + lane * 16;

    #pragma unroll 1
    for (int i = 0; i < NTW; ++i) {
        const int kt = w * NTW + ((i + rot) & 7);
        const char* img = himg + (size_t)kt * IMG_SZ;

        // ---- K frags -> time-shared kv buffer (32 VGPR)
        f16x8 kv[8];
        #pragma unroll
        for (int f = 0; f < 8; ++f)
            kv[f] = *(const f16x8*)(img + IMG_K + f * 1024);

        // ---- QK (swapped, 32x32x16) + exp2 + pack, per (qb, kb2)
        unsigned int wv[2][2][8];      // [qb][kb2][half*4+j] packed f16x2
        #pragma unroll
        for (int qb = 0; qb < 2; ++qb) {
            #pragma unroll
            for (int kb2 = 0; kb2 < 2; ++kb2) {
                __builtin_amdgcn_s_setprio(1);
                f32x16 s;
                s = __builtin_amdgcn_mfma_f32_32x32x16_f16(kv[kb2 * 4 + 0], qf[qb][0], cinit16, 0, 0, 0);
                s = __builtin_amdgcn_mfma_f32_32x32x16_f16(kv[kb2 * 4 + 1], qf[qb][1], s, 0, 0, 0);
                s = __builtin_amdgcn_mfma_f32_32x32x16_f16(kv[kb2 * 4 + 2], qf[qb][2], s, 0, 0, 0);
                s = __builtin_amdgcn_mfma_f32_32x32x16_f16(kv[kb2 * 4 + 3], qf[qb][3], s, 0, 0, 0);
                __builtin_amdgcn_s_setprio(0);
                float p[16];
                #pragma unroll
                for (int j = 0; j < 16; ++j) p[j] = __builtin_amdgcn_exp2f(s[j]);
                #pragma unroll
                for (int j = 0; j < 8; ++j) {
                    h16x2 wj = __builtin_amdgcn_cvt_pkrtz(p[2 * j], p[2 * j + 1]);
                    lac[qb] = __builtin_amdgcn_fdot2(wj, ones2, lac[qb], false);
                    wv[qb][kb2][j] = __builtin_bit_cast(unsigned int, wj);
                }
            }
        }

        // ---- V^T frags -> same kv regs (K dead after QK)
        #pragma unroll
        for (int f = 0; f < 8; ++f)
            kv[f] = *(const f16x8*)(img + IMG_V + f * 1024);

        // ---- PV (swapped, 32x32x16): chunk (kb2, half), A = V^T frag,
        //      B = own packed regs [half*4 .. half*4+3]
        __builtin_amdgcn_s_setprio(1);
        #pragma unroll
        for (int qb = 0; qb < 2; ++qb) {
            #pragma unroll
            for (int kb2 = 0; kb2 < 2; ++kb2) {
                #pragma unroll
                for (int half = 0; half < 2; ++half) {
                    i32x4 cb;
                    cb[0] = wv[qb][kb2][half * 4 + 0];
                    cb[1] = wv[qb][kb2][half * 4 + 1];
                    cb[2] = wv[qb][kb2][half * 4 + 2];
                    cb[3] = wv[qb][kb2][half * 4 + 3];
                    f16x8 B = __builtin_bit_cast(f16x8, cb);
                    #pragma unroll
                    for (int db = 0; db < 2; ++db)
                        o[qb][db] = __builtin_amdgcn_mfma_f32_32x32x16_f16(
                            kv[db * 4 + kb2 * 2 + half], B, o[qb][db], 0, 0, 0);
                }
            }
        }
        __builtin_amdgcn_s_setprio(0);
        // spill guard: keep next tile's loads out of this tile's body
        __builtin_amdgcn_sched_barrier(0);
    }

    // ---- l reduction: lane covers keys of its hg group -> one shfl
    lac[0] += __shfl_xor(lac[0], 32);
    lac[1] += __shfl_xor(lac[1], 32);

    // ---- split-K combine through LDS (stride-68 padded rows)
    float* Ls = Ob + 64 * 68;
    if (w == 1) {
        #pragma unroll
        for (int qb = 0; qb < 2; ++qb) {
            int q_loc = 32 * qb + q31;
            #pragma unroll
            for (int db = 0; db < 2; ++db)
                #pragma unroll
                for (int rq = 0; rq < 4; ++rq) {
                    int d0 = 32 * db + 8 * rq + 4 * hg;
                    float4 st;
                    st.x = o[qb][db][4 * rq + 0];
                    st.y = o[qb][db][4 * rq + 1];
                    st.z = o[qb][db][4 * rq + 2];
                    st.w = o[qb][db][4 * rq + 3];
                    *(float4*)&Ob[q_loc * 68 + d0] = st;
                }
            Ls[q_loc] = lac[qb];       // duplicate write across hg benign
        }
    }
    __syncthreads();

    if (w == 0) {
        #pragma unroll
        for (int qb = 0; qb < 2; ++qb) {
            int q_loc = 32 * qb + q31;
            float inv = 1.f / (lac[qb] + Ls[q_loc]);
            #pragma unroll
            for (int db = 0; db < 2; ++db)
                #pragma unroll
                for (int rq = 0; rq < 4; ++rq) {
                    int d0 = 32 * db + 8 * rq + 4 * hg;
                    float4 pb = *(const float4*)&Ob[q_loc * 68 + d0];
                    float4 st;
                    st.x = (o[qb][db][4 * rq + 0] + pb.x) * inv;
                    st.y = (o[qb][db][4 * rq + 1] + pb.y) * inv;
                    st.z = (o[qb][db][4 * rq + 2] + pb.z) * inv;
                    st.w = (o[qb][db][4 * rq + 3] + pb.w) * inv;
                    *(float4*)(outg + (size_t)(qbase + q_loc) * 1024 + hd * 64 + d0) = st;
                }
        }
    }
}

extern "C" void kernel_launch(void* const* d_in, const int* in_sizes, int n_in,
                              void* d_out, int out_size, void* d_ws, size_t ws_size,
                              hipStream_t stream) {
    const float* q = (const float*)d_in[0];
    const float* k = (const float*)d_in[1];
    const float* v = (const float*)d_in[2];
    float* out = (float*)d_out;
    char* ws = (char*)d_ws;   // 16*16*16384 = 4 MB

    prepass<<<dim3(NT, HEADS), dim3(256), 0, stream>>>(k, v, ws);
    ring_attn_v23<<<dim3(1024), dim3(128), 0, stream>>>(q, ws, out);
}

// Round 24
// 33.005 us; speedup vs baseline: 1.2616x; 1.0712x over previous
//
#include <hip/hip_runtime.h>

// TrueRingDilatedAttention R24 — R19 + full unroll (compiler cross-tile ILP).
// Identity 1: gathered K/V (4096) = each of 1024 local keys exactly 4x
//   -> softmax over 1024 distinct keys; denom = 4*S + EPS; out = 4*PV/denom.
// Identity 2: out = PV'/l' with p' = exp(s - 2) (shift-invariant).
// Identity 3: PV swapped, O^T = mfma(A=V^T, B=P^T), k-slots pi-permuted on
//   both operands so lane (g,c)'s B-frag is its OWN cvt_pkrtz output words.
// Identity 4: K scaled log2e/8 + QK C-init = -2*log2e -> p = exp2(s_out).
// R23 post-mortem: 32x32 fatter s-state hurt scheduling; not MFMA-bound.
// R24: the never-tried lever — drop `unroll 1` + tile-end sched_barrier so
//   LLVM schedules ACROSS tiles (PV(t) || loads/QK(t+1)). 8 identical bodies
//   -> allocator reuses transients; WRITE_SIZE is the spill sentinel.

typedef __attribute__((ext_vector_type(8))) _Float16 f16x8;   // 4 VGPRs
typedef __attribute__((ext_vector_type(2))) __fp16   h16x2;   // builtin type
typedef __attribute__((ext_vector_type(4))) float    f32x4;
typedef __attribute__((ext_vector_type(4))) int      i32x4;

constexpr int HEADS = 16;
constexpr int NQ    = 4096;
constexpr int NK    = 1024;
constexpr int KB    = 64;        // keys per tile
constexpr int NT    = NK / KB;   // 16 tiles total
constexpr int NTW   = NT / 2;    // 8 tiles per wave (2-way split-K)

constexpr int IMG_K  = 0;        // 8KB K fragment stream (QK^T A operand)
constexpr int IMG_V  = 8192;     // 8KB V^T A-frag stream (PV, pi-permuted k)
constexpr int IMG_SZ = 16384;

constexpr float KSCALE = 0.18033688011112042f;   // log2(e)/8
constexpr float CINIT  = -2.8853900817779268f;   // -2*log2(e)

// ---------------- pre-pass: build per-(h,kt) fragment streams ----------------
__global__ __launch_bounds__(256)
void prepass(const float* __restrict__ kg, const float* __restrict__ vg,
             char* __restrict__ ws)
{
    const int kt = blockIdx.x;
    const int h  = blockIdx.y;
    const int kb = kt * KB;
    char* img = ws + (size_t)(h * NT + kt) * IMG_SZ;
    const int tid = threadIdx.x;

    // K frags: unit u = f*64 + lane, f = t*2+cc.
    // lane (g,c) of frag (t,cc): K[kb+16t+c][32cc+8g+e], scaled log2e/8.
    #pragma unroll
    for (int i = 0; i < 2; ++i) {
        int u = i * 256 + tid;
        int f = u >> 6, l = u & 63;
        int t = f >> 1, cc = f & 1;
        int g = l >> 4, c = l & 15;
        const float* src = kg + (size_t)(kb + 16 * t + c) * 1024 + h * 64 + 32 * cc + 8 * g;
        float4 a = *(const float4*)src;
        float4 b = *(const float4*)(src + 4);
        f16x8 kk;
        kk[0] = (_Float16)(a.x * KSCALE); kk[1] = (_Float16)(a.y * KSCALE);
        kk[2] = (_Float16)(a.z * KSCALE); kk[3] = (_Float16)(a.w * KSCALE);
        kk[4] = (_Float16)(b.x * KSCALE); kk[5] = (_Float16)(b.y * KSCALE);
        kk[6] = (_Float16)(b.z * KSCALE); kk[7] = (_Float16)(b.w * KSCALE);
        *(f16x8*)(img + IMG_K + u * 16) = kk;
    }

    // V^T A-frags with k-permutation: unit u = f*64 + lane, f = m*4 + td.
    // lane (g,c), elem e: V[kb + 32m + 16*(e>>2) + 4g + (e&3)][h*64+16td+c]
    #pragma unroll
    for (int i = 0; i < 2; ++i) {
        int u = i * 256 + tid;
        int f = u >> 6, l = u & 63;
        int m = f >> 2, td = f & 3;
        int g = l >> 4, c = l & 15;
        f16x8 vv;
        #pragma unroll
        for (int e = 0; e < 8; ++e) {
            int key = kb + 32 * m + 16 * (e >> 2) + 4 * g + (e & 3);
            vv[e] = (_Float16)vg[(size_t)key * 1024 + h * 64 + 16 * td + c];
        }
        *(f16x8*)(img + IMG_V + u * 16) = vv;
    }
}

// --------- main: 64 q/wave, 2-wave split-K blocks, register-only P ---------
__global__ __launch_bounds__(128, 2)
void ring_attn_v24(const float* __restrict__ qg,
                   const char* __restrict__ ws,
                   float* __restrict__ outg)
{
    __shared__ __align__(16) float Ob[64 * 68 + 64];   // combine + Ls tail

    // XCD-aware swizzle: xcd = bid&7; each XCD runs heads {2*xcd, 2*xcd+1}.
    const int bid  = blockIdx.x;            // 0..1023
    const int xcd  = bid & 7;
    const int slot = bid >> 3;              // 0..127
    const int h    = xcd * 2 + (slot >> 6);
    const int qw   = slot & 63;             // q-block (64 q) within head

    const int tid  = threadIdx.x;
    const int w    = tid >> 6;         // split index: keys [w*512, w*512+512)
    const int lane = tid & 63;
    const int g    = lane >> 4;
    const int c    = lane & 15;
    const int qbase = qw * 64;

    // de-phase co-resident waves' tile rings
    const int rot  = ((bid >> 3) ^ (w << 2)) & 7;

    // ---- Q fragments fp16 (log2e/8 scale folded into K): 4 halves x 2 cc
    f16x8 qf[4][2];
    #pragma unroll
    for (int H = 0; H < 4; ++H)
        #pragma unroll
        for (int cc = 0; cc < 2; ++cc) {
            const float* src = qg + (size_t)(qbase + 16 * H + c) * 1024 + h * 64 + 32 * cc + 8 * g;
            float4 a = *(const float4*)src;
            float4 b = *(const float4*)(src + 4);
            f16x8 qq;
            qq[0] = (_Float16)a.x; qq[1] = (_Float16)a.y;
            qq[2] = (_Float16)a.z; qq[3] = (_Float16)a.w;
            qq[4] = (_Float16)b.x; qq[5] = (_Float16)b.y;
            qq[6] = (_Float16)b.z; qq[7] = (_Float16)b.w;
            qf[H][cc] = qq;
        }

    const f32x4 cinit = {CINIT, CINIT, CINIT, CINIT};
    const h16x2 ones2 = {(__fp16)1.f, (__fp16)1.f};

    f32x4 o[4][4];                     // [half][td] : O^T[d=16td+4g+r][q=c]
    #pragma unroll
    for (int H = 0; H < 4; ++H)
        #pragma unroll
        for (int td = 0; td < 4; ++td)
            #pragma unroll
            for (int r = 0; r < 4; ++r) o[H][td][r] = 0.f;
    float lac[4] = {0.f, 0.f, 0.f, 0.f};

    const char* himg = ws + (size_t)h * NT * IMG_SZ + lane * 16;

    #pragma unroll                      // FULL unroll: cross-tile scheduling
    for (int i = 0; i < NTW; ++i) {
        const int kt = w * NTW + ((i + rot) & 7);
        const char* img = himg + (size_t)kt * IMG_SZ;

        // ---- K frags -> time-shared kv buffer (32 VGPR)
        f16x8 kv[8];
        #pragma unroll
        for (int f = 0; f < 8; ++f)
            kv[f] = *(const f16x8*)(img + IMG_K + f * 1024);

        // ---- QK^T halves 0,1 (swapped: S[key][q]); C-init = -2*log2e
        f32x4 s0[4], s1[4], s2[4], s3[4];
        unsigned int wv[4][4][2];      // [half][t][rp] packed f16x2 of P
        __builtin_amdgcn_s_setprio(1);
        #pragma unroll
        for (int t = 0; t < 4; ++t) {
            s0[t] = __builtin_amdgcn_mfma_f32_16x16x32_f16(kv[2 * t],     qf[0][0], cinit, 0, 0, 0);
            s0[t] = __builtin_amdgcn_mfma_f32_16x16x32_f16(kv[2 * t + 1], qf[0][1], s0[t], 0, 0, 0);
            s1[t] = __builtin_amdgcn_mfma_f32_16x16x32_f16(kv[2 * t],     qf[1][0], cinit, 0, 0, 0);
            s1[t] = __builtin_amdgcn_mfma_f32_16x16x32_f16(kv[2 * t + 1], qf[1][1], s1[t], 0, 0, 0);
        }
        __builtin_amdgcn_s_setprio(0);
        // ---- exp2 + pack halves 0,1
        #pragma unroll
        for (int t = 0; t < 4; ++t) {
            float p0 = __builtin_amdgcn_exp2f(s0[t][0]);
            float p1 = __builtin_amdgcn_exp2f(s0[t][1]);
            float p2 = __builtin_amdgcn_exp2f(s0[t][2]);
            float p3 = __builtin_amdgcn_exp2f(s0[t][3]);
            h16x2 w0 = __builtin_amdgcn_cvt_pkrtz(p0, p1);
            h16x2 w1 = __builtin_amdgcn_cvt_pkrtz(p2, p3);
            lac[0] = __builtin_amdgcn_fdot2(w0, ones2, lac[0], false);
            lac[0] = __builtin_amdgcn_fdot2(w1, ones2, lac[0], false);
            wv[0][t][0] = __builtin_bit_cast(unsigned int, w0);
            wv[0][t][1] = __builtin_bit_cast(unsigned int, w1);
        }
        #pragma unroll
        for (int t = 0; t < 4; ++t) {
            float p0 = __builtin_amdgcn_exp2f(s1[t][0]);
            float p1 = __builtin_amdgcn_exp2f(s1[t][1]);
            float p2 = __builtin_amdgcn_exp2f(s1[t][2]);
            float p3 = __builtin_amdgcn_exp2f(s1[t][3]);
            h16x2 w0 = __builtin_amdgcn_cvt_pkrtz(p0, p1);
            h16x2 w1 = __builtin_amdgcn_cvt_pkrtz(p2, p3);
            lac[1] = __builtin_amdgcn_fdot2(w0, ones2, lac[1], false);
            lac[1] = __builtin_amdgcn_fdot2(w1, ones2, lac[1], false);
            wv[1][t][0] = __builtin_bit_cast(unsigned int, w0);
            wv[1][t][1] = __builtin_bit_cast(unsigned int, w1);
        }

        // ---- QK^T halves 2,3
        __builtin_amdgcn_s_setprio(1);
        #pragma unroll
        for (int t = 0; t < 4; ++t) {
            s2[t] = __builtin_amdgcn_mfma_f32_16x16x32_f16(kv[2 * t],     qf[2][0], cinit, 0, 0, 0);
            s2[t] = __builtin_amdgcn_mfma_f32_16x16x32_f16(kv[2 * t + 1], qf[2][1], s2[t], 0, 0, 0);
            s3[t] = __builtin_amdgcn_mfma_f32_16x16x32_f16(kv[2 * t],     qf[3][0], cinit, 0, 0, 0);
            s3[t] = __builtin_amdgcn_mfma_f32_16x16x32_f16(kv[2 * t + 1], qf[3][1], s3[t], 0, 0, 0);
        }
        __builtin_amdgcn_s_setprio(0);

        // ---- V^T A-frags -> same kv regs (K dead); hides under exp23
        #pragma unroll
        for (int f = 0; f < 8; ++f)
            kv[f] = *(const f16x8*)(img + IMG_V + f * 1024);

        // ---- exp2 + pack halves 2,3
        #pragma unroll
        for (int t = 0; t < 4; ++t) {
            float p0 = __builtin_amdgcn_exp2f(s2[t][0]);
            float p1 = __builtin_amdgcn_exp2f(s2[t][1]);
            float p2 = __builtin_amdgcn_exp2f(s2[t][2]);
            float p3 = __builtin_amdgcn_exp2f(s2[t][3]);
            h16x2 w0 = __builtin_amdgcn_cvt_pkrtz(p0, p1);
            h16x2 w1 = __builtin_amdgcn_cvt_pkrtz(p2, p3);
            lac[2] = __builtin_amdgcn_fdot2(w0, ones2, lac[2], false);
            lac[2] = __builtin_amdgcn_fdot2(w1, ones2, lac[2], false);
            wv[2][t][0] = __builtin_bit_cast(unsigned int, w0);
            wv[2][t][1] = __builtin_bit_cast(unsigned int, w1);
        }
        #pragma unroll
        for (int t = 0; t < 4; ++t) {
            float p0 = __builtin_amdgcn_exp2f(s3[t][0]);
            float p1 = __builtin_amdgcn_exp2f(s3[t][1]);
            float p2 = __builtin_amdgcn_exp2f(s3[t][2]);
            float p3 = __builtin_amdgcn_exp2f(s3[t][3]);
            h16x2 w0 = __builtin_amdgcn_cvt_pkrtz(p0, p1);
            h16x2 w1 = __builtin_amdgcn_cvt_pkrtz(p2, p3);
            lac[3] = __builtin_amdgcn_fdot2(w0, ones2, lac[3], false);
            lac[3] = __builtin_amdgcn_fdot2(w1, ones2, lac[3], false);
            wv[3][t][0] = __builtin_bit_cast(unsigned int, w0);
            wv[3][t][1] = __builtin_bit_cast(unsigned int, w1);
        }

        // ---- PV swapped: O^T += mfma(A=V^T frag, B=own packed P words)
        __builtin_amdgcn_s_setprio(1);
        #pragma unroll
        for (int H = 0; H < 4; ++H) {
            i32x4 c0, c1;
            c0[0] = wv[H][0][0]; c0[1] = wv[H][0][1];
            c0[2] = wv[H][1][0]; c0[3] = wv[H][1][1];
            c1[0] = wv[H][2][0]; c1[1] = wv[H][2][1];
            c1[2] = wv[H][3][0]; c1[3] = wv[H][3][1];
            f16x8 B0 = __builtin_bit_cast(f16x8, c0);   // keys 0..31 (pi-order)
            f16x8 B1 = __builtin_bit_cast(f16x8, c1);   // keys 32..63
            #pragma unroll
            for (int td = 0; td < 4; ++td) {
                o[H][td] = __builtin_amdgcn_mfma_f32_16x16x32_f16(kv[td],     B0, o[H][td], 0, 0, 0);
                o[H][td] = __builtin_amdgcn_mfma_f32_16x16x32_f16(kv[4 + td], B1, o[H][td], 0, 0, 0);
            }
        }
        __builtin_amdgcn_s_setprio(0);
        // NOTE: no sched_barrier — compiler free to overlap next tile's loads
        // and QK with this tile's PV. Spill sentinel = WRITE_SIZE.
    }

    // ---- reduce l across g-groups: every lane gets full l for q = own c
    #pragma unroll
    for (int H = 0; H < 4; ++H) {
        lac[H] += __shfl_xor(lac[H], 16);
        lac[H] += __shfl_xor(lac[H], 32);
    }

    // ---- split-K combine through LDS (stride-68 padded rows)
    float* Ls = Ob + 64 * 68;
    if (w == 1) {
        #pragma unroll
        for (int H = 0; H < 4; ++H)
            #pragma unroll
            for (int td = 0; td < 4; ++td) {
                float4 st;
                st.x = o[H][td][0]; st.y = o[H][td][1];
                st.z = o[H][td][2]; st.w = o[H][td][3];
                *(float4*)&Ob[(16 * H + c) * 68 + 16 * td + 4 * g] = st;
            }
        if (lane < 16) {
            #pragma unroll
            for (int H = 0; H < 4; ++H) Ls[16 * H + lane] = lac[H];
        }
    }
    __syncthreads();

    if (w == 0) {
        #pragma unroll
        for (int H = 0; H < 4; ++H) {
            float inv = 1.f / (lac[H] + Ls[16 * H + c]);
            #pragma unroll
            for (int td = 0; td < 4; ++td) {
                float4 pb = *(const float4*)&Ob[(16 * H + c) * 68 + 16 * td + 4 * g];
                float4 st;
                st.x = (o[H][td][0] + pb.x) * inv;
                st.y = (o[H][td][1] + pb.y) * inv;
                st.z = (o[H][td][2] + pb.z) * inv;
                st.w = (o[H][td][3] + pb.w) * inv;
                *(float4*)(outg + (size_t)(qbase + 16 * H + c) * 1024 + h * 64 + 16 * td + 4 * g) = st;
            }
        }
    }
}

extern "C" void kernel_launch(void* const* d_in, const int* in_sizes, int n_in,
                              void* d_out, int out_size, void* d_ws, size_t ws_size,
                              hipStream_t stream) {
    const float* q = (const float*)d_in[0];
    const float* k = (const float*)d_in[1];
    const float* v = (const float*)d_in[2];
    float* out = (float*)d_out;
    char* ws = (char*)d_ws;   // 16*16*16384 = 4 MB

    prepass<<<dim3(NT, HEADS), dim3(256), 0, stream>>>(k, v, ws);
    ring_attn_v24<<<dim3(1024), dim3(128), 0, stream>>>(q, ws, out);
}